// Round 1
// baseline (811.598 us; speedup 1.0000x reference)
//
#include <hip/hip_runtime.h>
#include <math.h>

#define NN 25000      // nodes
#define NE 400000     // edges
#define DD 128        // hidden dim
#define HD 384        // heads * dim
#define NEG 0.2f
#define EPS 1e-5f

// ---------------- CSR construction (grouped by dst, self-loop first) ----------------

__global__ void k_init_count(int* __restrict__ cnt) {
    int i = blockIdx.x * 256 + threadIdx.x;
    if (i < NN) cnt[i] = 1;   // 1 = the self loop
}

__global__ void k_count(const int* __restrict__ dst, int* __restrict__ cnt) {
    int e = blockIdx.x * 256 + threadIdx.x;
    if (e < NE) atomicAdd(&cnt[dst[e]], 1);
}

// single-block scan, 1024 threads, Hillis-Steele per 1024-chunk
__global__ void k_scan(const int* __restrict__ cnt, int* __restrict__ row_ptr) {
    __shared__ int sh[1024];
    int carry = 0;
    for (int base = 0; base < NN; base += 1024) {
        int i = base + (int)threadIdx.x;
        int v = (i < NN) ? cnt[i] : 0;
        sh[threadIdx.x] = v;
        __syncthreads();
        for (int o = 1; o < 1024; o <<= 1) {
            int t = (threadIdx.x >= (unsigned)o) ? sh[threadIdx.x - o] : 0;
            __syncthreads();
            sh[threadIdx.x] += t;
            __syncthreads();
        }
        if (i < NN) row_ptr[i + 1] = carry + sh[threadIdx.x];
        carry += sh[1023];
        __syncthreads();
    }
    if (threadIdx.x == 0) row_ptr[0] = 0;
}

__global__ void k_fill_self(const int* __restrict__ row_ptr, int* __restrict__ col_src,
                            int* __restrict__ cur) {
    int i = blockIdx.x * 256 + threadIdx.x;
    if (i < NN) { int p = row_ptr[i]; col_src[p] = i; cur[i] = p + 1; }
}

__global__ void k_fill_edges(const int* __restrict__ src, const int* __restrict__ dst,
                             int* __restrict__ cur, int* __restrict__ col_src) {
    int e = blockIdx.x * 256 + threadIdx.x;
    if (e < NE) { int p = atomicAdd(&cur[dst[e]], 1); col_src[p] = src[e]; }
}

// ---------------- fp32 tiled GEMM: C[M,N] = A[M,K] @ B[K,N] (+bias) (or += if acc) --------

__global__ __launch_bounds__(256) void k_gemm(const float* __restrict__ A,
                                              const float* __restrict__ B,
                                              const float* __restrict__ bias,
                                              float* __restrict__ C,
                                              int M, int N, int K, int accFlag) {
    __shared__ float sA[16][68];   // [k][m], pad keeps float4 alignment, 2-way bank max
    __shared__ float sB[16][68];   // [k][n]
    int tid = threadIdx.x;
    int tx = tid & 15, ty = tid >> 4;
    int mb = blockIdx.y * 64;
    int nb = blockIdx.x * 64;
    float acc[4][4] = {};
    for (int k0 = 0; k0 < K; k0 += 16) {
        {   // A tile: 64 rows x 16 k
            int flat = tid * 4;
            int r = flat >> 4, c = flat & 15;
            int gr = mb + r;
            float4 v = make_float4(0.f, 0.f, 0.f, 0.f);
            if (gr < M) v = *(const float4*)(A + (size_t)gr * K + k0 + c);
            sA[c + 0][r] = v.x; sA[c + 1][r] = v.y; sA[c + 2][r] = v.z; sA[c + 3][r] = v.w;
        }
        {   // B tile: 16 k x 64 cols
            int flat = tid * 4;
            int r = flat >> 6, c = flat & 63;
            *(float4*)&sB[r][c] = *(const float4*)(B + (size_t)(k0 + r) * N + nb + c);
        }
        __syncthreads();
#pragma unroll
        for (int kk = 0; kk < 16; ++kk) {
            float a[4], b[4];
            *(float4*)a = *(const float4*)&sA[kk][ty * 4];
            *(float4*)b = *(const float4*)&sB[kk][tx * 4];
#pragma unroll
            for (int i = 0; i < 4; ++i)
#pragma unroll
                for (int j = 0; j < 4; ++j) acc[i][j] += a[i] * b[j];
        }
        __syncthreads();
    }
#pragma unroll
    for (int i = 0; i < 4; ++i) {
        int r = mb + ty * 4 + i;
        if (r < M) {
#pragma unroll
            for (int j = 0; j < 4; ++j) {
                int c = nb + tx * 4 + j;
                float v = acc[i][j];
                if (accFlag) C[(size_t)r * N + c] += v;
                else { if (bias) v += bias[c]; C[(size_t)r * N + c] = v; }
            }
        }
    }
}

// ---------------- GATv2 aggregate: one wave per dst node, online softmax ----------------
// lane holds 6 dims: head h=j>>1 at dim (j>>1)*128 + (j&1)*64 + lane
__global__ __launch_bounds__(256) void k_gat(const float* __restrict__ xl,
                                             const float* __restrict__ xr,
                                             const float* __restrict__ att,
                                             const float* __restrict__ bias,
                                             const int* __restrict__ row_ptr,
                                             const int* __restrict__ col_src,
                                             float* __restrict__ out) {
    int node = blockIdx.x * 4 + (threadIdx.x >> 6);
    int lane = threadIdx.x & 63;
    if (node >= NN) return;
    size_t base = (size_t)node * HD;
    int dj[6];
    float xr_r[6], att_r[6], acc[6];
#pragma unroll
    for (int j = 0; j < 6; ++j) {
        dj[j] = (j >> 1) * 128 + (j & 1) * 64 + lane;
        xr_r[j] = xr[base + dj[j]];
        att_r[j] = att[dj[j]];
        acc[j] = 0.f;
    }
    float m0 = -INFINITY, m1 = -INFINITY, m2 = -INFINITY;
    float l0 = 0.f, l1 = 0.f, l2 = 0.f;
    int e0 = row_ptr[node], e1 = row_ptr[node + 1];
    for (int e = e0; e < e1; ++e) {
        int s = col_src[e];
        size_t sb = (size_t)s * HD;
        float xls[6];
#pragma unroll
        for (int j = 0; j < 6; ++j) xls[j] = xl[sb + dj[j]];
        float p0, p1, p2, v, t;
        v = xls[0] + xr_r[0]; t = v > 0.f ? v : NEG * v; p0 = t * att_r[0];
        v = xls[1] + xr_r[1]; t = v > 0.f ? v : NEG * v; p0 += t * att_r[1];
        v = xls[2] + xr_r[2]; t = v > 0.f ? v : NEG * v; p1 = t * att_r[2];
        v = xls[3] + xr_r[3]; t = v > 0.f ? v : NEG * v; p1 += t * att_r[3];
        v = xls[4] + xr_r[4]; t = v > 0.f ? v : NEG * v; p2 = t * att_r[4];
        v = xls[5] + xr_r[5]; t = v > 0.f ? v : NEG * v; p2 += t * att_r[5];
#pragma unroll
        for (int o = 32; o >= 1; o >>= 1) {
            p0 += __shfl_xor(p0, o);
            p1 += __shfl_xor(p1, o);
            p2 += __shfl_xor(p2, o);
        }
        float mn0 = fmaxf(m0, p0), c0 = __expf(m0 - mn0), w0 = __expf(p0 - mn0);
        float mn1 = fmaxf(m1, p1), c1 = __expf(m1 - mn1), w1 = __expf(p1 - mn1);
        float mn2 = fmaxf(m2, p2), c2 = __expf(m2 - mn2), w2 = __expf(p2 - mn2);
        l0 = l0 * c0 + w0; l1 = l1 * c1 + w1; l2 = l2 * c2 + w2;
        m0 = mn0; m1 = mn1; m2 = mn2;
        acc[0] = acc[0] * c0 + w0 * xls[0];
        acc[1] = acc[1] * c0 + w0 * xls[1];
        acc[2] = acc[2] * c1 + w1 * xls[2];
        acc[3] = acc[3] * c1 + w1 * xls[3];
        acc[4] = acc[4] * c2 + w2 * xls[4];
        acc[5] = acc[5] * c2 + w2 * xls[5];
    }
    float r0 = 1.f / l0, r1 = 1.f / l1, r2 = 1.f / l2;
    out[base + dj[0]] = acc[0] * r0 + bias[dj[0]];
    out[base + dj[1]] = acc[1] * r0 + bias[dj[1]];
    out[base + dj[2]] = acc[2] * r1 + bias[dj[2]];
    out[base + dj[3]] = acc[3] * r1 + bias[dj[3]];
    out[base + dj[4]] = acc[4] * r2 + bias[dj[4]];
    out[base + dj[5]] = acc[5] * r2 + bias[dj[5]];
}

// ---------------- BatchNorm (axis=0 over N rows, 128 cols) ----------------

__global__ void k_zero(float* __restrict__ p) {
    p[threadIdx.x] = 0.f;   // 256 floats: sum[128], sumsq[128]
}

__global__ void k_bn_stats(const float* __restrict__ y, float* __restrict__ stats) {
    int col = threadIdx.x & 127;
    int half = threadIdx.x >> 7;
    float s = 0.f, q = 0.f;
    for (int r = blockIdx.x * 2 + half; r < NN; r += gridDim.x * 2) {
        float v = y[(size_t)r * DD + col];
        s += v; q += v * v;
    }
    __shared__ float sh[256], shq[256];
    sh[threadIdx.x] = s; shq[threadIdx.x] = q;
    __syncthreads();
    if (half == 0) {
        atomicAdd(&stats[col], sh[col] + sh[col + 128]);
        atomicAdd(&stats[128 + col], shq[col] + shq[col + 128]);
    }
}

// stats[0..127]=sum, [128..255]=sumsq -> writes [256..383]=scale, [384..511]=shift
__global__ void k_bn_finalize(float* __restrict__ stats, const float* __restrict__ g,
                              const float* __restrict__ be) {
    int c = threadIdx.x;
    if (c < 128) {
        float minv = 1.f / (float)NN;
        float mu = stats[c] * minv;
        float var = stats[128 + c] * minv - mu * mu;
        float sc = g[c] * rsqrtf(var + EPS);
        stats[256 + c] = sc;
        stats[384 + c] = be[c] - mu * sc;
    }
}

__global__ void k_bn_apply(float* __restrict__ y, const float* __restrict__ stats) {
    int idx = blockIdx.x * 256 + threadIdx.x;
    if (idx < NN * DD) {
        int c = idx & 127;
        float v = y[idx] * stats[256 + c] + stats[384 + c];
        y[idx] = fmaxf(v, 0.f);
    }
}

// ---------------- launch ----------------

extern "C" void kernel_launch(void* const* d_in, const int* in_sizes, int n_in,
                              void* d_out, int out_size, void* d_ws, size_t ws_size,
                              hipStream_t stream) {
    const float* x    = (const float*)d_in[0];
    const int*   ei   = (const int*)d_in[1];
    const float* Wl1  = (const float*)d_in[2];
    const float* bl1  = (const float*)d_in[3];
    const float* Wr1  = (const float*)d_in[4];
    const float* br1  = (const float*)d_in[5];
    const float* att1 = (const float*)d_in[6];
    const float* bc1  = (const float*)d_in[7];
    const float* g1   = (const float*)d_in[8];
    const float* be1  = (const float*)d_in[9];
    const float* Wl2  = (const float*)d_in[10];
    const float* bl2  = (const float*)d_in[11];
    const float* Wr2  = (const float*)d_in[12];
    const float* br2  = (const float*)d_in[13];
    const float* att2 = (const float*)d_in[14];
    const float* bc2  = (const float*)d_in[15];
    const float* g2   = (const float*)d_in[16];
    const float* be2  = (const float*)d_in[17];
    const float* W1   = (const float*)d_in[18];
    const float* b1   = (const float*)d_in[19];
    const float* W2   = (const float*)d_in[20];
    const float* b2   = (const float*)d_in[21];
    const int* esrc = ei;
    const int* edst = ei + NE;

    float* f    = (float*)d_ws;
    float* bufA = f;              // xl  [NN,384]  38.4 MB
    float* bufB = f + 9600000;    // xr / h2 (in-place)
    float* bufC = f + 19200000;   // x_in (persists for concat)
    float* bufD = f + 28800000;   // y1 / h [NN,128]
    float* stats = f + 32000000;  // 512 floats
    int* ip      = (int*)(f + 32000512);
    int* row_ptr = ip;                    // NN+1
    int* cnt     = ip + 25002;            // count, then reused as fill cursor
    int* col_src = ip + 25002 + 25000;    // NE+NN
    float* out   = (float*)d_out;

    // CSR (rebuilt every call — same work each call)
    k_init_count<<<(NN + 255) / 256, 256, 0, stream>>>(cnt);
    k_count<<<(NE + 255) / 256, 256, 0, stream>>>(edst, cnt);
    k_scan<<<1, 1024, 0, stream>>>(cnt, row_ptr);
    k_fill_self<<<(NN + 255) / 256, 256, 0, stream>>>(row_ptr, col_src, cnt);
    k_fill_edges<<<(NE + 255) / 256, 256, 0, stream>>>(esrc, edst, cnt, col_src);

    dim3 blk(256);
    dim3 g384(HD / 64, (NN + 63) / 64);
    dim3 g128(DD / 64, (NN + 63) / 64);

    // layer 1
    k_gemm<<<g384, blk, 0, stream>>>(x, Wl1, bl1, bufA, NN, HD, DD, 0);
    k_gemm<<<g384, blk, 0, stream>>>(x, Wr1, br1, bufB, NN, HD, DD, 0);
    k_gat<<<(NN + 3) / 4, 256, 0, stream>>>(bufA, bufB, att1, bc1, row_ptr, col_src, bufC);

    // mid MLP + BN + relu
    k_gemm<<<g128, blk, 0, stream>>>(bufC, W1, b1, bufD, NN, DD, HD, 0);
    k_zero<<<1, 256, 0, stream>>>(stats);
    k_bn_stats<<<128, 256, 0, stream>>>(bufD, stats);
    k_bn_finalize<<<1, 128, 0, stream>>>(stats, g1, be1);
    k_bn_apply<<<(NN * DD + 255) / 256, 256, 0, stream>>>(bufD, stats);

    // layer 2 (h2 written in-place over xr buffer: each wave reads only its own dst row)
    k_gemm<<<g384, blk, 0, stream>>>(bufD, Wl2, bl2, bufA, NN, HD, DD, 0);
    k_gemm<<<g384, blk, 0, stream>>>(bufD, Wr2, br2, bufB, NN, HD, DD, 0);
    k_gat<<<(NN + 3) / 4, 256, 0, stream>>>(bufA, bufB, att2, bc2, row_ptr, col_src, bufB);

    // final: concat([h2, x_in]) @ W2 + b2 == h2@W2[:384] + x_in@W2[384:] + b2
    k_gemm<<<g128, blk, 0, stream>>>(bufB, W2, b2, out, NN, DD, HD, 0);
    k_gemm<<<g128, blk, 0, stream>>>(bufC, W2 + (size_t)HD * DD, nullptr, out, NN, DD, HD, 1);
    k_zero<<<1, 256, 0, stream>>>(stats);
    k_bn_stats<<<128, 256, 0, stream>>>(out, stats);
    k_bn_finalize<<<1, 128, 0, stream>>>(stats, g2, be2);
    k_bn_apply<<<(NN * DD + 255) / 256, 256, 0, stream>>>(out, stats);
}

// Round 2
// 589.468 us; speedup vs baseline: 1.3768x; 1.3768x over previous
//
#include <hip/hip_runtime.h>
#include <math.h>

#define NN 25000      // nodes
#define NE 400000     // edges
#define DD 128        // hidden dim
#define HD 384        // heads * dim
#define NEG 0.2f
#define EPS 1e-5f

typedef unsigned int u32;
typedef unsigned short u16;
typedef __attribute__((ext_vector_type(8))) short short8;   // 8 bf16 (4 VGPRs)
typedef __attribute__((ext_vector_type(4))) float floatx4;  // MFMA accumulator

// ---- bf16 helpers (RNE) ----
__device__ __forceinline__ u32 bf16_1(float x) {
    u32 u = __float_as_uint(x);
    return (u + 0x7fffu + ((u >> 16) & 1u)) >> 16;
}
__device__ __forceinline__ float blo(u32 u) { return __uint_as_float(u << 16); }
__device__ __forceinline__ float bhi(u32 u) { return __uint_as_float(u & 0xffff0000u); }

// ---------------- CSR construction (grouped by dst, self-loop first) ----------------

__global__ void k_init_count(int* __restrict__ cnt) {
    int i = blockIdx.x * 256 + threadIdx.x;
    if (i < NN) cnt[i] = 1;   // 1 = the self loop
}

__global__ void k_count(const int* __restrict__ dst, int* __restrict__ cnt) {
    int e = blockIdx.x * 256 + threadIdx.x;
    if (e < NE) atomicAdd(&cnt[dst[e]], 1);
}

// parallel 3-phase scan: block sums -> scan sums -> per-block scan + offset
__global__ void k_scan1(const int* __restrict__ cnt, int* __restrict__ bsum) {
    __shared__ int sh[256];
    int i = blockIdx.x * 256 + threadIdx.x;
    sh[threadIdx.x] = (i < NN) ? cnt[i] : 0;
    __syncthreads();
    for (int o = 128; o >= 1; o >>= 1) {
        if ((int)threadIdx.x < o) sh[threadIdx.x] += sh[threadIdx.x + o];
        __syncthreads();
    }
    if (threadIdx.x == 0) bsum[blockIdx.x] = sh[0];
}

__global__ void k_scan2(int* __restrict__ bsum, int nblk) {
    __shared__ int sh[128];
    int v = ((int)threadIdx.x < nblk) ? bsum[threadIdx.x] : 0;
    sh[threadIdx.x] = v;
    __syncthreads();
    for (int o = 1; o < 128; o <<= 1) {
        int t = (threadIdx.x >= (unsigned)o) ? sh[threadIdx.x - o] : 0;
        __syncthreads();
        sh[threadIdx.x] += t;
        __syncthreads();
    }
    if ((int)threadIdx.x < nblk) bsum[threadIdx.x] = sh[threadIdx.x];
}

__global__ void k_scan3(const int* __restrict__ cnt, const int* __restrict__ bsum,
                        int* __restrict__ row_ptr) {
    __shared__ int sh[256];
    int i = blockIdx.x * 256 + threadIdx.x;
    sh[threadIdx.x] = (i < NN) ? cnt[i] : 0;
    __syncthreads();
    for (int o = 1; o < 256; o <<= 1) {
        int t = (threadIdx.x >= (unsigned)o) ? sh[threadIdx.x - o] : 0;
        __syncthreads();
        sh[threadIdx.x] += t;
        __syncthreads();
    }
    int base = blockIdx.x ? bsum[blockIdx.x - 1] : 0;
    if (i < NN) row_ptr[i + 1] = base + sh[threadIdx.x];
    if (i == 0) row_ptr[0] = 0;
}

__global__ void k_fill_self(const int* __restrict__ row_ptr, int* __restrict__ col_src,
                            int* __restrict__ cur) {
    int i = blockIdx.x * 256 + threadIdx.x;
    if (i < NN) { int p = row_ptr[i]; col_src[p] = i; cur[i] = p + 1; }
}

__global__ void k_fill_edges(const int* __restrict__ src, const int* __restrict__ dst,
                             int* __restrict__ cur, int* __restrict__ col_src) {
    int e = blockIdx.x * 256 + threadIdx.x;
    if (e < NE) { int p = atomicAdd(&cur[dst[e]], 1); col_src[p] = src[e]; }
}

// ---------------- casts ----------------

__global__ void k_cast(const float* __restrict__ in, u16* __restrict__ out, int n) {
    int i = blockIdx.x * 256 + threadIdx.x;
    if (i < n) out[i] = (u16)bf16_1(in[i]);
}

// fp32 [K][N] row-major -> bf16 [N][K]
__global__ void k_castT(const float* __restrict__ W, u16* __restrict__ WT, int K, int N) {
    int i = blockIdx.x * 256 + threadIdx.x;
    if (i < K * N) {
        int k = i / N, n = i - k * N;
        WT[n * K + k] = (u16)bf16_1(W[i]);
    }
}

// ---------------- bf16 MFMA GEMM: C[M,N] = A[M,K] @ BT[N,K]^T (+bias) ----------------
// BM=128 BN=64 BK=64, 256 threads (4 waves), wave w -> rows [w*32,w*32+32) x 64 cols.
// LDS layout [K/8][rows][8] keeps ds_read_b128 frag reads + float4 staging conflict-free.
__global__ __launch_bounds__(256) void k_gemm_bf(
        const u16* __restrict__ A, const u16* __restrict__ BT,
        const float* __restrict__ bias,
        float* __restrict__ Cf, u16* __restrict__ Cb,
        int M, int N, int K, int lda) {
    __shared__ short sA[8][128][8];
    __shared__ short sB[8][64][8];
    int tid = threadIdx.x;
    int wid = tid >> 6, lane = tid & 63;
    int quad = lane >> 4, m16 = lane & 15;
    int mb = blockIdx.y * 128, nb = blockIdx.x * 64;

    floatx4 acc[2][4];
#pragma unroll
    for (int mf = 0; mf < 2; ++mf)
#pragma unroll
        for (int nf = 0; nf < 4; ++nf)
#pragma unroll
            for (int r = 0; r < 4; ++r) acc[mf][nf][r] = 0.f;

    for (int k0 = 0; k0 < K; k0 += 64) {
        // stage A: 128 rows x 64 k (1024 x 16B units)
#pragma unroll
        for (int i = 0; i < 4; ++i) {
            int u = tid + i * 256;
            int r = u >> 3, c8 = u & 7;
            int gr = mb + r; gr = gr < M ? gr : M - 1;
            *(float4*)(&sA[c8][r][0]) =
                *(const float4*)(const void*)(A + (size_t)gr * lda + k0 + c8 * 8);
        }
        // stage B: 64 rows x 64 k (512 x 16B units)
#pragma unroll
        for (int i = 0; i < 2; ++i) {
            int u = tid + i * 256;
            int r = u >> 3, c8 = u & 7;
            *(float4*)(&sB[c8][r][0]) =
                *(const float4*)(const void*)(BT + (size_t)(nb + r) * K + k0 + c8 * 8);
        }
        __syncthreads();
#pragma unroll
        for (int ks = 0; ks < 2; ++ks) {
            short8 a0 = *(const short8*)(&sA[ks * 4 + quad][wid * 32 + m16][0]);
            short8 a1 = *(const short8*)(&sA[ks * 4 + quad][wid * 32 + 16 + m16][0]);
            short8 b0 = *(const short8*)(&sB[ks * 4 + quad][m16][0]);
            short8 b1 = *(const short8*)(&sB[ks * 4 + quad][16 + m16][0]);
            short8 b2 = *(const short8*)(&sB[ks * 4 + quad][32 + m16][0]);
            short8 b3 = *(const short8*)(&sB[ks * 4 + quad][48 + m16][0]);
            acc[0][0] = __builtin_amdgcn_mfma_f32_16x16x32_bf16(a0, b0, acc[0][0], 0, 0, 0);
            acc[0][1] = __builtin_amdgcn_mfma_f32_16x16x32_bf16(a0, b1, acc[0][1], 0, 0, 0);
            acc[0][2] = __builtin_amdgcn_mfma_f32_16x16x32_bf16(a0, b2, acc[0][2], 0, 0, 0);
            acc[0][3] = __builtin_amdgcn_mfma_f32_16x16x32_bf16(a0, b3, acc[0][3], 0, 0, 0);
            acc[1][0] = __builtin_amdgcn_mfma_f32_16x16x32_bf16(a1, b0, acc[1][0], 0, 0, 0);
            acc[1][1] = __builtin_amdgcn_mfma_f32_16x16x32_bf16(a1, b1, acc[1][1], 0, 0, 0);
            acc[1][2] = __builtin_amdgcn_mfma_f32_16x16x32_bf16(a1, b2, acc[1][2], 0, 0, 0);
            acc[1][3] = __builtin_amdgcn_mfma_f32_16x16x32_bf16(a1, b3, acc[1][3], 0, 0, 0);
        }
        __syncthreads();
    }
    // epilogue: C/D layout col=lane&15, row=quad*4+reg (m89-verified)
#pragma unroll
    for (int mf = 0; mf < 2; ++mf) {
        int rbase = mb + wid * 32 + mf * 16 + quad * 4;
#pragma unroll
        for (int nf = 0; nf < 4; ++nf) {
            int col = nb + nf * 16 + m16;
            float bv = bias ? bias[col] : 0.f;
#pragma unroll
            for (int r = 0; r < 4; ++r) {
                int row = rbase + r;
                if (row < M) {
                    float v = acc[mf][nf][r] + bv;
                    if (Cf) Cf[(size_t)row * N + col] = v;
                    if (Cb) Cb[(size_t)row * N + col] = (u16)bf16_1(v);
                }
            }
        }
    }
}

// ---------------- GATv2 aggregate: one wave per dst node, online softmax ----------------
// xl/xr bf16 packed as dwords: uint j = h*64+lane holds dims (h*128+2*lane, +1).
// outb: packed-dword bf16 out, row stride 384 uints (=768 bf16), base pre-offset by caller.
__global__ __launch_bounds__(256) void k_gat(const u32* __restrict__ xl,
                                             const u32* __restrict__ xr,
                                             const float* __restrict__ att,
                                             const float* __restrict__ bias,
                                             const int* __restrict__ row_ptr,
                                             const int* __restrict__ col_src,
                                             u32* __restrict__ outb) {
    int node = blockIdx.x * 4 + (threadIdx.x >> 6);
    int lane = threadIdx.x & 63;
    if (node >= NN) return;
    int base32 = node * 192;
    float xr_f[6], att_f[6], bi[6], acc[6];
#pragma unroll
    for (int h = 0; h < 3; ++h) {
        u32 ur = xr[base32 + h * 64 + lane];
        xr_f[h * 2] = blo(ur); xr_f[h * 2 + 1] = bhi(ur);
        float2 av = *(const float2*)&att[h * 128 + 2 * lane];
        att_f[h * 2] = av.x; att_f[h * 2 + 1] = av.y;
        float2 bv = *(const float2*)&bias[h * 128 + 2 * lane];
        bi[h * 2] = bv.x; bi[h * 2 + 1] = bv.y;
        acc[h * 2] = 0.f; acc[h * 2 + 1] = 0.f;
    }
    float m0 = -INFINITY, m1 = -INFINITY, m2 = -INFINITY;
    float l0 = 0.f, l1 = 0.f, l2 = 0.f;
    int e0 = row_ptr[node], e1 = row_ptr[node + 1];
    // prefetch first edge (>=1 edge guaranteed: self loop)
    int s = col_src[e0];
    u32 u0 = xl[s * 192 + lane], u1 = xl[s * 192 + 64 + lane], u2 = xl[s * 192 + 128 + lane];
    for (int e = e0; e < e1;) {
        float x0 = blo(u0), x1 = bhi(u0), x2 = blo(u1), x3 = bhi(u1), x4 = blo(u2), x5 = bhi(u2);
        ++e;
        if (e < e1) {   // prefetch next edge's row while we compute
            int s2 = col_src[e];
            int b2 = s2 * 192 + lane;
            u0 = xl[b2]; u1 = xl[b2 + 64]; u2 = xl[b2 + 128];
        }
        float p0, p1, p2, v, t;
        v = x0 + xr_f[0]; t = fmaxf(v, 0.f) + NEG * fminf(v, 0.f); p0 = t * att_f[0];
        v = x1 + xr_f[1]; t = fmaxf(v, 0.f) + NEG * fminf(v, 0.f); p0 += t * att_f[1];
        v = x2 + xr_f[2]; t = fmaxf(v, 0.f) + NEG * fminf(v, 0.f); p1 = t * att_f[2];
        v = x3 + xr_f[3]; t = fmaxf(v, 0.f) + NEG * fminf(v, 0.f); p1 += t * att_f[3];
        v = x4 + xr_f[4]; t = fmaxf(v, 0.f) + NEG * fminf(v, 0.f); p2 = t * att_f[4];
        v = x5 + xr_f[5]; t = fmaxf(v, 0.f) + NEG * fminf(v, 0.f); p2 += t * att_f[5];
#pragma unroll
        for (int o = 32; o >= 1; o >>= 1) {
            p0 += __shfl_xor(p0, o);
            p1 += __shfl_xor(p1, o);
            p2 += __shfl_xor(p2, o);
        }
        float mn0 = fmaxf(m0, p0), c0 = __expf(m0 - mn0), w0 = __expf(p0 - mn0);
        float mn1 = fmaxf(m1, p1), c1 = __expf(m1 - mn1), w1 = __expf(p1 - mn1);
        float mn2 = fmaxf(m2, p2), c2 = __expf(m2 - mn2), w2 = __expf(p2 - mn2);
        l0 = l0 * c0 + w0; l1 = l1 * c1 + w1; l2 = l2 * c2 + w2;
        m0 = mn0; m1 = mn1; m2 = mn2;
        acc[0] = acc[0] * c0 + w0 * x0;
        acc[1] = acc[1] * c0 + w0 * x1;
        acc[2] = acc[2] * c1 + w1 * x2;
        acc[3] = acc[3] * c1 + w1 * x3;
        acc[4] = acc[4] * c2 + w2 * x4;
        acc[5] = acc[5] * c2 + w2 * x5;
    }
    float r0 = 1.f / l0, r1 = 1.f / l1, r2 = 1.f / l2;
    int ob = node * 384;
    outb[ob + lane]       = bf16_1(acc[0] * r0 + bi[0]) | (bf16_1(acc[1] * r0 + bi[1]) << 16);
    outb[ob + 64 + lane]  = bf16_1(acc[2] * r1 + bi[2]) | (bf16_1(acc[3] * r1 + bi[3]) << 16);
    outb[ob + 128 + lane] = bf16_1(acc[4] * r2 + bi[4]) | (bf16_1(acc[5] * r2 + bi[5]) << 16);
}

// ---------------- BatchNorm (axis=0 over N rows, 128 cols) ----------------

__global__ void k_zero(float* __restrict__ p) {
    p[threadIdx.x] = 0.f;   // 256 floats: sum[128], sumsq[128]
}

__global__ void k_bn_stats(const float* __restrict__ y, float* __restrict__ stats) {
    int col = threadIdx.x & 127;
    int half = threadIdx.x >> 7;
    float s = 0.f, q = 0.f;
    for (int r = blockIdx.x * 2 + half; r < NN; r += gridDim.x * 2) {
        float v = y[(size_t)r * DD + col];
        s += v; q += v * v;
    }
    __shared__ float sh[256], shq[256];
    sh[threadIdx.x] = s; shq[threadIdx.x] = q;
    __syncthreads();
    if (half == 0) {
        atomicAdd(&stats[col], sh[col] + sh[col + 128]);
        atomicAdd(&stats[128 + col], shq[col] + shq[col + 128]);
    }
}

__global__ void k_bn_finalize(float* __restrict__ stats, const float* __restrict__ g,
                              const float* __restrict__ be) {
    int c = threadIdx.x;
    if (c < 128) {
        float minv = 1.f / (float)NN;
        float mu = stats[c] * minv;
        float var = stats[128 + c] * minv - mu * mu;
        float sc = g[c] * rsqrtf(var + EPS);
        stats[256 + c] = sc;
        stats[384 + c] = be[c] - mu * sc;
    }
}

// relu(y*sc+sh) -> optionally fp32 in-place, optionally bf16 copy
__global__ void k_bn_apply(float* __restrict__ y, const float* __restrict__ stats,
                           u16* __restrict__ yb, int wf) {
    int idx = blockIdx.x * 256 + threadIdx.x;
    if (idx < NN * DD) {
        int c = idx & 127;
        float v = fmaxf(y[idx] * stats[256 + c] + stats[384 + c], 0.f);
        if (wf) y[idx] = v;
        if (yb) yb[idx] = (u16)bf16_1(v);
    }
}

// ---------------- launch ----------------

extern "C" void kernel_launch(void* const* d_in, const int* in_sizes, int n_in,
                              void* d_out, int out_size, void* d_ws, size_t ws_size,
                              hipStream_t stream) {
    const float* x    = (const float*)d_in[0];
    const int*   ei   = (const int*)d_in[1];
    const float* Wl1  = (const float*)d_in[2];
    const float* bl1  = (const float*)d_in[3];
    const float* Wr1  = (const float*)d_in[4];
    const float* br1  = (const float*)d_in[5];
    const float* att1 = (const float*)d_in[6];
    const float* bc1  = (const float*)d_in[7];
    const float* g1   = (const float*)d_in[8];
    const float* be1  = (const float*)d_in[9];
    const float* Wl2  = (const float*)d_in[10];
    const float* bl2  = (const float*)d_in[11];
    const float* Wr2  = (const float*)d_in[12];
    const float* br2  = (const float*)d_in[13];
    const float* att2 = (const float*)d_in[14];
    const float* bc2  = (const float*)d_in[15];
    const float* g2   = (const float*)d_in[16];
    const float* be2  = (const float*)d_in[17];
    const float* W1   = (const float*)d_in[18];
    const float* b1   = (const float*)d_in[19];
    const float* W2   = (const float*)d_in[20];
    const float* b2   = (const float*)d_in[21];
    const int* esrc = ei;
    const int* edst = ei + NE;
    float* out = (float*)d_out;

    // ---- workspace layout (all 16B-aligned) ----
    float* bufD   = (float*)d_ws;          // y1 / h fp32 [NN,128]   12.8 MB
    float* stats  = bufD + 3200000;        // 512 f
    int* row_ptr  = (int*)(stats + 512);   // 25002
    int* cnt      = row_ptr + 25002;       // 25000
    int* col_src  = cnt + 25000;           // 425000
    int* bsum     = col_src + 425000;      // 128 + 2 pad -> 130
    u16* xb       = (u16*)(bsum + 130);    // x bf16 [NN,128]        6.4 MB
    u16* bufA     = xb + 3200000;          // xl bf16 [NN,384]      19.2 MB
    u16* bufB     = bufA + 9600000;        // xr bf16 [NN,384]      19.2 MB
    u16* bufCat   = bufB + 9600000;        // [NN,768]: h2 | x_in   38.4 MB
    u16* bufDb    = bufCat + 19200000;     // h bf16 [NN,128]        6.4 MB
    u16* Wl1T     = bufDb + 3200000;       // [384][128]
    u16* Wr1T     = Wl1T + 49152;
    u16* W1T      = Wr1T + 49152;          // [128][384]
    u16* Wl2T     = W1T + 49152;
    u16* Wr2T     = Wl2T + 49152;
    u16* W2T      = Wr2T + 49152;          // [128][768]

    // CSR (rebuilt every call — identical work each call)
    k_init_count<<<(NN + 255) / 256, 256, 0, stream>>>(cnt);
    k_count<<<(NE + 255) / 256, 256, 0, stream>>>(edst, cnt);
    k_scan1<<<98, 256, 0, stream>>>(cnt, bsum);
    k_scan2<<<1, 128, 0, stream>>>(bsum, 98);
    k_scan3<<<98, 256, 0, stream>>>(cnt, bsum, row_ptr);
    k_fill_self<<<(NN + 255) / 256, 256, 0, stream>>>(row_ptr, col_src, cnt);
    k_fill_edges<<<(NE + 255) / 256, 256, 0, stream>>>(esrc, edst, cnt, col_src);

    // casts
    k_cast<<<(3200000 + 255) / 256, 256, 0, stream>>>(x, xb, 3200000);
    k_castT<<<192, 256, 0, stream>>>(Wl1, Wl1T, 128, 384);
    k_castT<<<192, 256, 0, stream>>>(Wr1, Wr1T, 128, 384);
    k_castT<<<192, 256, 0, stream>>>(W1, W1T, 384, 128);
    k_castT<<<192, 256, 0, stream>>>(Wl2, Wl2T, 128, 384);
    k_castT<<<192, 256, 0, stream>>>(Wr2, Wr2T, 128, 384);
    k_castT<<<384, 256, 0, stream>>>(W2, W2T, 768, 128);

    dim3 blk(256);
    dim3 g384(6, (NN + 127) / 128);
    dim3 g128(2, (NN + 127) / 128);

    // layer 1: xl/xr (bf16 out only)
    k_gemm_bf<<<g384, blk, 0, stream>>>(xb, Wl1T, bl1, nullptr, bufA, NN, HD, DD, DD);
    k_gemm_bf<<<g384, blk, 0, stream>>>(xb, Wr1T, br1, nullptr, bufB, NN, HD, DD, DD);
    k_gat<<<(NN + 3) / 4, 256, 0, stream>>>((const u32*)bufA, (const u32*)bufB, att1, bc1,
                                            row_ptr, col_src, (u32*)bufCat + 192);

    // mid MLP + BN + relu (A = x_in at bufCat cols 384.., lda=768)
    k_gemm_bf<<<g128, blk, 0, stream>>>(bufCat + 384, W1T, b1, bufD, nullptr, NN, DD, HD, 768);
    k_zero<<<1, 256, 0, stream>>>(stats);
    k_bn_stats<<<128, 256, 0, stream>>>(bufD, stats);
    k_bn_finalize<<<1, 128, 0, stream>>>(stats, g1, be1);
    k_bn_apply<<<(NN * DD + 255) / 256, 256, 0, stream>>>(bufD, stats, bufDb, 0);

    // layer 2
    k_gemm_bf<<<g384, blk, 0, stream>>>(bufDb, Wl2T, bl2, nullptr, bufA, NN, HD, DD, DD);
    k_gemm_bf<<<g384, blk, 0, stream>>>(bufDb, Wr2T, br2, nullptr, bufB, NN, HD, DD, DD);
    k_gat<<<(NN + 3) / 4, 256, 0, stream>>>((const u32*)bufA, (const u32*)bufB, att2, bc2,
                                            row_ptr, col_src, (u32*)bufCat);

    // final: concat([h2, x_in]) @ W2 + b2 as ONE K=768 GEMM, then BN+relu
    k_gemm_bf<<<g128, blk, 0, stream>>>(bufCat, W2T, b2, out, nullptr, NN, DD, 768, 768);
    k_zero<<<1, 256, 0, stream>>>(stats);
    k_bn_stats<<<128, 256, 0, stream>>>(out, stats);
    k_bn_finalize<<<1, 128, 0, stream>>>(stats, g2, be2);
    k_bn_apply<<<(NN * DD + 255) / 256, 256, 0, stream>>>(out, stats, nullptr, 1);
}

// Round 3
// 503.933 us; speedup vs baseline: 1.6105x; 1.1697x over previous
//
#include <hip/hip_runtime.h>
#include <math.h>

#define NN 25000      // nodes
#define NE 400000     // edges
#define DD 128        // hidden dim
#define HD 384        // heads * dim
#define NEG 0.2f
#define EPS 1e-5f

typedef unsigned int u32;
typedef unsigned short u16;
typedef __attribute__((ext_vector_type(8))) short short8;   // 8 bf16 (4 VGPRs)
typedef __attribute__((ext_vector_type(4))) float floatx4;  // MFMA accumulator

// ---- bf16 helpers (RNE) ----
__device__ __forceinline__ u32 bf16_1(float x) {
    u32 u = __float_as_uint(x);
    return (u + 0x7fffu + ((u >> 16) & 1u)) >> 16;
}
__device__ __forceinline__ float blo(u32 u) { return __uint_as_float(u << 16); }
__device__ __forceinline__ float bhi(u32 u) { return __uint_as_float(u & 0xffff0000u); }

__device__ __forceinline__ void unpack8(uint4 u, float* f) {
    f[0] = blo(u.x); f[1] = bhi(u.x); f[2] = blo(u.y); f[3] = bhi(u.y);
    f[4] = blo(u.z); f[5] = bhi(u.z); f[6] = blo(u.w); f[7] = bhi(u.w);
}

// ---------------- CSR construction (grouped by dst) ----------------

__global__ void k_init_count(int* __restrict__ cnt, float* __restrict__ stats) {
    int i = blockIdx.x * 256 + threadIdx.x;
    if (i < NN) cnt[i] = 1;   // 1 = the self loop
    if (blockIdx.x == 0) {
#pragma unroll
        for (int j = 0; j < 4; ++j) stats[threadIdx.x + j * 256] = 0.f;
    }
}

__global__ void k_count(const int* __restrict__ dst, int* __restrict__ cnt) {
    int e = blockIdx.x * 256 + threadIdx.x;
    if (e < NE) atomicAdd(&cnt[dst[e]], 1);
}

__global__ void k_scan1(const int* __restrict__ cnt, int* __restrict__ bsum) {
    __shared__ int sh[256];
    int i = blockIdx.x * 256 + threadIdx.x;
    sh[threadIdx.x] = (i < NN) ? cnt[i] : 0;
    __syncthreads();
    for (int o = 128; o >= 1; o >>= 1) {
        if ((int)threadIdx.x < o) sh[threadIdx.x] += sh[threadIdx.x + o];
        __syncthreads();
    }
    if (threadIdx.x == 0) bsum[blockIdx.x] = sh[0];
}

__global__ void k_scan2(int* __restrict__ bsum, int nblk) {
    __shared__ int sh[128];
    int v = ((int)threadIdx.x < nblk) ? bsum[threadIdx.x] : 0;
    sh[threadIdx.x] = v;
    __syncthreads();
    for (int o = 1; o < 128; o <<= 1) {
        int t = (threadIdx.x >= (unsigned)o) ? sh[threadIdx.x - o] : 0;
        __syncthreads();
        sh[threadIdx.x] += t;
        __syncthreads();
    }
    if ((int)threadIdx.x < nblk) bsum[threadIdx.x] = sh[threadIdx.x];
}

// scan3 + fill_self fused: row_ptr[i] is available in-block (exclusive = incl - v)
__global__ void k_scan3(const int* __restrict__ cnt, const int* __restrict__ bsum,
                        int* __restrict__ row_ptr, int* __restrict__ col_src,
                        int* __restrict__ cur) {
    __shared__ int sh[256];
    int i = blockIdx.x * 256 + threadIdx.x;
    int v = (i < NN) ? cnt[i] : 0;
    sh[threadIdx.x] = v;
    __syncthreads();
    for (int o = 1; o < 256; o <<= 1) {
        int t = (threadIdx.x >= (unsigned)o) ? sh[threadIdx.x - o] : 0;
        __syncthreads();
        sh[threadIdx.x] += t;
        __syncthreads();
    }
    int base = blockIdx.x ? bsum[blockIdx.x - 1] : 0;
    if (i < NN) {
        int incl = base + sh[threadIdx.x];
        row_ptr[i + 1] = incl;
        int p = incl - v;          // exclusive prefix = row start
        col_src[p] = i;            // self loop first
        cur[i] = p + 1;
    }
    if (i == 0) row_ptr[0] = 0;
}

__global__ void k_fill_edges(const int* __restrict__ src, const int* __restrict__ dst,
                             int* __restrict__ cur, int* __restrict__ col_src) {
    int e = blockIdx.x * 256 + threadIdx.x;
    if (e < NE) { int p = atomicAdd(&cur[dst[e]], 1); col_src[p] = src[e]; }
}

// ---------------- one cast kernel for everything ----------------
// regions (elements): x 3200000 | Wl1 49152 | Wr1 49152 | W1 49152 | Wl2 49152
//                     | Wr2 49152 | W2 98304 | fb1 768 | fb2 768   (all %256==0)
__global__ void k_cast_all(const float* __restrict__ x,
                           const float* __restrict__ Wl1, const float* __restrict__ Wr1,
                           const float* __restrict__ W1,
                           const float* __restrict__ Wl2, const float* __restrict__ Wr2,
                           const float* __restrict__ W2,
                           const float* __restrict__ bl1, const float* __restrict__ br1,
                           const float* __restrict__ bl2, const float* __restrict__ br2,
                           u16* __restrict__ xb, u16* __restrict__ WfT1,
                           u16* __restrict__ W1T, u16* __restrict__ WfT2,
                           u16* __restrict__ W2T,
                           float* __restrict__ fb1, float* __restrict__ fb2) {
    int i = blockIdx.x * 256 + threadIdx.x;
    if (i < 3200000) { xb[i] = (u16)bf16_1(x[i]); return; }
    i -= 3200000;
    if (i < 49152) { int k = i / 384, n = i - k * 384; WfT1[n * 128 + k] = (u16)bf16_1(Wl1[i]); return; }
    i -= 49152;
    if (i < 49152) { int k = i / 384, n = i - k * 384; WfT1[(384 + n) * 128 + k] = (u16)bf16_1(Wr1[i]); return; }
    i -= 49152;
    if (i < 49152) { int k = i / 128, n = i - k * 128; W1T[n * 384 + k] = (u16)bf16_1(W1[i]); return; }
    i -= 49152;
    if (i < 49152) { int k = i / 384, n = i - k * 384; WfT2[n * 128 + k] = (u16)bf16_1(Wl2[i]); return; }
    i -= 49152;
    if (i < 49152) { int k = i / 384, n = i - k * 384; WfT2[(384 + n) * 128 + k] = (u16)bf16_1(Wr2[i]); return; }
    i -= 49152;
    if (i < 98304) { int k = i / 128, n = i - k * 128; W2T[n * 768 + k] = (u16)bf16_1(W2[i]); return; }
    i -= 98304;
    if (i < 768) { fb1[i] = (i < 384) ? bl1[i] : br1[i - 384]; return; }
    i -= 768;
    if (i < 768) { fb2[i] = (i < 384) ? bl2[i] : br2[i - 384]; }
}
#define CAST_TOTAL (3200000 + 5 * 49152 + 98304 + 1536)

// ---------------- bf16 MFMA GEMM: C[M,N] = A[M,K] @ BT[N,K]^T (+bias) ----------------
__global__ __launch_bounds__(256) void k_gemm_bf(
        const u16* __restrict__ A, const u16* __restrict__ BT,
        const float* __restrict__ bias,
        float* __restrict__ Cf, u16* __restrict__ Cb,
        int M, int N, int K, int lda) {
    __shared__ short sA[8][128][8];
    __shared__ short sB[8][64][8];
    int tid = threadIdx.x;
    int wid = tid >> 6, lane = tid & 63;
    int quad = lane >> 4, m16 = lane & 15;
    int mb = blockIdx.y * 128, nb = blockIdx.x * 64;

    floatx4 acc[2][4];
#pragma unroll
    for (int mf = 0; mf < 2; ++mf)
#pragma unroll
        for (int nf = 0; nf < 4; ++nf)
#pragma unroll
            for (int r = 0; r < 4; ++r) acc[mf][nf][r] = 0.f;

    for (int k0 = 0; k0 < K; k0 += 64) {
#pragma unroll
        for (int i = 0; i < 4; ++i) {
            int u = tid + i * 256;
            int r = u >> 3, c8 = u & 7;
            int gr = mb + r; gr = gr < M ? gr : M - 1;
            *(float4*)(&sA[c8][r][0]) =
                *(const float4*)(const void*)(A + (size_t)gr * lda + k0 + c8 * 8);
        }
#pragma unroll
        for (int i = 0; i < 2; ++i) {
            int u = tid + i * 256;
            int r = u >> 3, c8 = u & 7;
            *(float4*)(&sB[c8][r][0]) =
                *(const float4*)(const void*)(BT + (size_t)(nb + r) * K + k0 + c8 * 8);
        }
        __syncthreads();
#pragma unroll
        for (int ks = 0; ks < 2; ++ks) {
            short8 a0 = *(const short8*)(&sA[ks * 4 + quad][wid * 32 + m16][0]);
            short8 a1 = *(const short8*)(&sA[ks * 4 + quad][wid * 32 + 16 + m16][0]);
            short8 b0 = *(const short8*)(&sB[ks * 4 + quad][m16][0]);
            short8 b1 = *(const short8*)(&sB[ks * 4 + quad][16 + m16][0]);
            short8 b2 = *(const short8*)(&sB[ks * 4 + quad][32 + m16][0]);
            short8 b3 = *(const short8*)(&sB[ks * 4 + quad][48 + m16][0]);
            acc[0][0] = __builtin_amdgcn_mfma_f32_16x16x32_bf16(a0, b0, acc[0][0], 0, 0, 0);
            acc[0][1] = __builtin_amdgcn_mfma_f32_16x16x32_bf16(a0, b1, acc[0][1], 0, 0, 0);
            acc[0][2] = __builtin_amdgcn_mfma_f32_16x16x32_bf16(a0, b2, acc[0][2], 0, 0, 0);
            acc[0][3] = __builtin_amdgcn_mfma_f32_16x16x32_bf16(a0, b3, acc[0][3], 0, 0, 0);
            acc[1][0] = __builtin_amdgcn_mfma_f32_16x16x32_bf16(a1, b0, acc[1][0], 0, 0, 0);
            acc[1][1] = __builtin_amdgcn_mfma_f32_16x16x32_bf16(a1, b1, acc[1][1], 0, 0, 0);
            acc[1][2] = __builtin_amdgcn_mfma_f32_16x16x32_bf16(a1, b2, acc[1][2], 0, 0, 0);
            acc[1][3] = __builtin_amdgcn_mfma_f32_16x16x32_bf16(a1, b3, acc[1][3], 0, 0, 0);
        }
        __syncthreads();
    }
#pragma unroll
    for (int mf = 0; mf < 2; ++mf) {
        int rbase = mb + wid * 32 + mf * 16 + quad * 4;
#pragma unroll
        for (int nf = 0; nf < 4; ++nf) {
            int col = nb + nf * 16 + m16;
            float bv = bias ? bias[col] : 0.f;
#pragma unroll
            for (int r = 0; r < 4; ++r) {
                int row = rbase + r;
                if (row < M) {
                    float v = acc[mf][nf][r] + bv;
                    if (Cf) Cf[(size_t)row * N + col] = v;
                    if (Cb) Cb[(size_t)row * N + col] = (u16)bf16_1(v);
                }
            }
        }
    }
}

// ---------------- GATv2 aggregate: one wave per dst, 4 edge streams of 16 lanes --------
// xlr: [NN][384] dwords per row; dwords 0-191 = xl (bf16 pairs), 192-383 = xr.
// Lane (g,gl): group g processes edges e0+g, e0+g+4, ...; lane gl holds dims
// [8gl, 8gl+8) of every head (dwordx4 at 64h + 4gl). Flash-merge of the 4
// group states at the end (shfl_xor 16, 32) with -1e30 empty-group sentinel.
// outb: row stride 384 dwords, caller pre-offsets for the column slot.
__global__ __launch_bounds__(256) void k_gat(const u32* __restrict__ xlr,
                                             const float* __restrict__ att,
                                             const float* __restrict__ bias,
                                             const int* __restrict__ row_ptr,
                                             const int* __restrict__ col_src,
                                             u32* __restrict__ outb) {
    int node = blockIdx.x * 4 + (threadIdx.x >> 6);
    int lane = threadIdx.x & 63;
    if (node >= NN) return;
    int g = lane >> 4, gl = lane & 15;

    const u32* xrp = xlr + (size_t)node * 384 + 192 + 4 * gl;
    float xr_f[3][8], att_f[3][8], acc[3][8];
    float m[3], l[3];
#pragma unroll
    for (int h = 0; h < 3; ++h) {
        uint4 ur = *(const uint4*)(xrp + h * 64);
        unpack8(ur, xr_f[h]);
        *(float4*)&att_f[h][0] = *(const float4*)&att[h * 128 + 8 * gl];
        *(float4*)&att_f[h][4] = *(const float4*)&att[h * 128 + 8 * gl + 4];
#pragma unroll
        for (int k = 0; k < 8; ++k) acc[h][k] = 0.f;
        m[h] = -1e30f; l[h] = 0.f;
    }

    int e0 = row_ptr[node];
    int cntE = row_ptr[node + 1] - e0;

    uint4 u0 = {}, u1 = {}, u2 = {};
    if (g < cntE) {
        int s = col_src[e0 + g];
        const u32* xp = xlr + (size_t)s * 384 + 4 * gl;
        u0 = *(const uint4*)(xp);
        u1 = *(const uint4*)(xp + 64);
        u2 = *(const uint4*)(xp + 128);
    }
    for (int t = g; t < cntE; t += 4) {
        float xv[3][8];
        unpack8(u0, xv[0]); unpack8(u1, xv[1]); unpack8(u2, xv[2]);
        int tn = t + 4;
        if (tn < cntE) {   // prefetch next edge in this group's stream
            int s = col_src[e0 + tn];
            const u32* xp = xlr + (size_t)s * 384 + 4 * gl;
            u0 = *(const uint4*)(xp);
            u1 = *(const uint4*)(xp + 64);
            u2 = *(const uint4*)(xp + 128);
        }
        float p[3];
#pragma unroll
        for (int h = 0; h < 3; ++h) {
            float ph = 0.f;
#pragma unroll
            for (int k = 0; k < 8; ++k) {
                float v = xv[h][k] + xr_f[h][k];
                float lt = fmaxf(v, 0.f) + NEG * fminf(v, 0.f);
                ph += lt * att_f[h][k];
            }
            p[h] = ph;
        }
#pragma unroll
        for (int o = 1; o <= 8; o <<= 1) {
            p[0] += __shfl_xor(p[0], o);
            p[1] += __shfl_xor(p[1], o);
            p[2] += __shfl_xor(p[2], o);
        }
#pragma unroll
        for (int h = 0; h < 3; ++h) {
            float mn = fmaxf(m[h], p[h]);
            float c = __expf(m[h] - mn), w = __expf(p[h] - mn);
            l[h] = l[h] * c + w;
            m[h] = mn;
#pragma unroll
            for (int k = 0; k < 8; ++k) acc[h][k] = acc[h][k] * c + w * xv[h][k];
        }
    }

    // merge the 4 group states (empty group: m=-1e30, l=0, acc=0 -> exact zeros)
#pragma unroll
    for (int o = 16; o <= 32; o <<= 1) {
#pragma unroll
        for (int h = 0; h < 3; ++h) {
            float mo = __shfl_xor(m[h], o);
            float lo = __shfl_xor(l[h], o);
            float mn = fmaxf(m[h], mo);
            float cs = __expf(m[h] - mn);
            float co = __expf(mo - mn);
            l[h] = l[h] * cs + lo * co;
            m[h] = mn;
#pragma unroll
            for (int k = 0; k < 8; ++k)
                acc[h][k] = acc[h][k] * cs + __shfl_xor(acc[h][k], o) * co;
        }
    }

    if (g == 0) {
        u32* op = outb + (size_t)node * 384 + 4 * gl;
#pragma unroll
        for (int h = 0; h < 3; ++h) {
            float r = 1.f / l[h];
            float bv[8];
            *(float4*)&bv[0] = *(const float4*)&bias[h * 128 + 8 * gl];
            *(float4*)&bv[4] = *(const float4*)&bias[h * 128 + 8 * gl + 4];
            uint4 w;
            w.x = bf16_1(acc[h][0] * r + bv[0]) | (bf16_1(acc[h][1] * r + bv[1]) << 16);
            w.y = bf16_1(acc[h][2] * r + bv[2]) | (bf16_1(acc[h][3] * r + bv[3]) << 16);
            w.z = bf16_1(acc[h][4] * r + bv[4]) | (bf16_1(acc[h][5] * r + bv[5]) << 16);
            w.w = bf16_1(acc[h][6] * r + bv[6]) | (bf16_1(acc[h][7] * r + bv[7]) << 16);
            *(uint4*)(op + h * 64) = w;
        }
    }
}

// ---------------- BatchNorm (axis=0 over N rows, 128 cols) ----------------

__global__ void k_bn_stats(const float* __restrict__ y, float* __restrict__ stats) {
    int col = threadIdx.x & 127;
    int half = threadIdx.x >> 7;
    float s = 0.f, q = 0.f;
    for (int r = blockIdx.x * 2 + half; r < NN; r += gridDim.x * 2) {
        float v = y[(size_t)r * DD + col];
        s += v; q += v * v;
    }
    __shared__ float sh[256], shq[256];
    sh[threadIdx.x] = s; shq[threadIdx.x] = q;
    __syncthreads();
    if (half == 0) {
        atomicAdd(&stats[col], sh[col] + sh[col + 128]);
        atomicAdd(&stats[128 + col], shq[col] + shq[col + 128]);
    }
}

__global__ void k_bn_finalize(float* __restrict__ stats, const float* __restrict__ g,
                              const float* __restrict__ be) {
    int c = threadIdx.x;
    if (c < 128) {
        float minv = 1.f / (float)NN;
        float mu = stats[c] * minv;
        float var = stats[128 + c] * minv - mu * mu;
        float sc = g[c] * rsqrtf(var + EPS);
        stats[256 + c] = sc;
        stats[384 + c] = be[c] - mu * sc;
    }
}

__global__ void k_bn_apply(float* __restrict__ y, const float* __restrict__ stats,
                           u16* __restrict__ yb, int wf) {
    int idx = blockIdx.x * 256 + threadIdx.x;
    if (idx < NN * DD) {
        int c = idx & 127;
        float v = fmaxf(y[idx] * stats[256 + c] + stats[384 + c], 0.f);
        if (wf) y[idx] = v;
        if (yb) yb[idx] = (u16)bf16_1(v);
    }
}

// ---------------- launch ----------------

extern "C" void kernel_launch(void* const* d_in, const int* in_sizes, int n_in,
                              void* d_out, int out_size, void* d_ws, size_t ws_size,
                              hipStream_t stream) {
    const float* x    = (const float*)d_in[0];
    const int*   ei   = (const int*)d_in[1];
    const float* Wl1  = (const float*)d_in[2];
    const float* bl1  = (const float*)d_in[3];
    const float* Wr1  = (const float*)d_in[4];
    const float* br1  = (const float*)d_in[5];
    const float* att1 = (const float*)d_in[6];
    const float* bc1  = (const float*)d_in[7];
    const float* g1   = (const float*)d_in[8];
    const float* be1  = (const float*)d_in[9];
    const float* Wl2  = (const float*)d_in[10];
    const float* bl2  = (const float*)d_in[11];
    const float* Wr2  = (const float*)d_in[12];
    const float* br2  = (const float*)d_in[13];
    const float* att2 = (const float*)d_in[14];
    const float* bc2  = (const float*)d_in[15];
    const float* g2   = (const float*)d_in[16];
    const float* be2  = (const float*)d_in[17];
    const float* W1   = (const float*)d_in[18];
    const float* b1   = (const float*)d_in[19];
    const float* W2   = (const float*)d_in[20];
    const float* b2   = (const float*)d_in[21];
    const int* esrc = ei;
    const int* edst = ei + NE;
    float* out = (float*)d_out;

    // ---- workspace layout (all regions 16B-aligned) ----
    float* bufD   = (float*)d_ws;          // mid fp32 [NN,128]      12.8 MB
    float* stats  = bufD + 3200000;        // 1024 f (BN1: +0, BN2: +512)
    int* row_ptr  = (int*)(stats + 1024);  // 25002
    int* cnt      = row_ptr + 25002;       // 25000
    int* col_src  = cnt + 25000;           // 425000
    int* bsum     = col_src + 425000;      // 132 (pad)
    float* fb1    = (float*)(bsum + 132);  // 768 fused bias L1
    float* fb2    = fb1 + 768;             // 768 fused bias L2
    u16* xb       = (u16*)(fb2 + 768);     // x bf16 [NN,128]         6.4 MB
    u16* XLR      = xb + 3200000;          // [NN,768] xl|xr bf16    38.4 MB
    u16* bufCat   = XLR + 19200000;        // [NN,768] h2|x_in bf16  38.4 MB
    u16* bufDb    = bufCat + 19200000;     // h bf16 [NN,128]         6.4 MB
    u16* WfT1     = bufDb + 3200000;       // [768][128]
    u16* W1T      = WfT1 + 98304;          // [128][384]
    u16* WfT2     = W1T + 49152;           // [768][128]
    u16* W2T      = WfT2 + 98304;          // [128][768]

    // CSR (rebuilt every call — identical work each call)
    k_init_count<<<98, 256, 0, stream>>>(cnt, stats);
    k_count<<<(NE + 255) / 256, 256, 0, stream>>>(edst, cnt);
    k_scan1<<<98, 256, 0, stream>>>(cnt, bsum);
    k_scan2<<<1, 128, 0, stream>>>(bsum, 98);
    k_scan3<<<98, 256, 0, stream>>>(cnt, bsum, row_ptr, col_src, cnt);
    k_fill_edges<<<(NE + 255) / 256, 256, 0, stream>>>(esrc, edst, cnt, col_src);

    // all casts + weight transposes + fused biases, one kernel
    k_cast_all<<<(CAST_TOTAL + 255) / 256, 256, 0, stream>>>(
        x, Wl1, Wr1, W1, Wl2, Wr2, W2, bl1, br1, bl2, br2,
        xb, WfT1, W1T, WfT2, W2T, fb1, fb2);

    dim3 blk(256);
    dim3 g768(12, (NN + 127) / 128);
    dim3 g128(2, (NN + 127) / 128);

    // layer 1: fused [xl|xr] = x @ [Wl1|Wr1]  -> XLR
    k_gemm_bf<<<g768, blk, 0, stream>>>(xb, WfT1, fb1, nullptr, XLR, NN, 768, DD, DD);
    k_gat<<<(NN + 3) / 4, 256, 0, stream>>>((const u32*)XLR, att1, bc1,
                                            row_ptr, col_src, (u32*)bufCat + 192);

    // mid MLP + BN + relu  (A = x_in at bufCat cols 384.., lda=768)
    k_gemm_bf<<<g128, blk, 0, stream>>>(bufCat + 384, W1T, b1, bufD, nullptr, NN, DD, HD, 768);
    k_bn_stats<<<128, 256, 0, stream>>>(bufD, stats);
    k_bn_finalize<<<1, 128, 0, stream>>>(stats, g1, be1);
    k_bn_apply<<<(NN * DD + 255) / 256, 256, 0, stream>>>(bufD, stats, bufDb, 0);

    // layer 2
    k_gemm_bf<<<g768, blk, 0, stream>>>(bufDb, WfT2, fb2, nullptr, XLR, NN, 768, DD, DD);
    k_gat<<<(NN + 3) / 4, 256, 0, stream>>>((const u32*)XLR, att2, bc2,
                                            row_ptr, col_src, (u32*)bufCat);

    // final: concat([h2, x_in]) @ W2 + b2 as one K=768 GEMM, then BN+relu
    k_gemm_bf<<<g128, blk, 0, stream>>>(bufCat, W2T, b2, out, nullptr, NN, DD, 768, 768);
    k_bn_stats<<<128, 256, 0, stream>>>(out, stats + 512);
    k_bn_finalize<<<1, 128, 0, stream>>>(stats + 512, g2, be2);
    k_bn_apply<<<(NN * DD + 255) / 256, 256, 0, stream>>>(out, stats + 512, nullptr, 1);
}

// Round 4
// 485.219 us; speedup vs baseline: 1.6726x; 1.0386x over previous
//
#include <hip/hip_runtime.h>
#include <math.h>

#define NN 25000      // nodes
#define NE 400000     // edges
#define DD 128        // hidden dim
#define HD 384        // heads * dim
#define NEG 0.2f
#define EPS 1e-5f

typedef unsigned int u32;
typedef unsigned short u16;
typedef __attribute__((ext_vector_type(8))) short short8;   // 8 bf16 (4 VGPRs)
typedef __attribute__((ext_vector_type(4))) float floatx4;  // MFMA accumulator

// ---- bf16 helpers (RNE) ----
__device__ __forceinline__ u32 bf16_1(float x) {
    u32 u = __float_as_uint(x);
    return (u + 0x7fffu + ((u >> 16) & 1u)) >> 16;
}
__device__ __forceinline__ float blo(u32 u) { return __uint_as_float(u << 16); }
__device__ __forceinline__ float bhi(u32 u) { return __uint_as_float(u & 0xffff0000u); }

// ---------------- CSR construction (grouped by dst) ----------------

__global__ void k_count(const int* __restrict__ dst, int* __restrict__ cnt) {
    int e = blockIdx.x * 256 + threadIdx.x;
    if (e < NE) atomicAdd(&cnt[dst[e]], 1);
}

__global__ void k_scan1(const int* __restrict__ cnt, int* __restrict__ bsum) {
    __shared__ int sh[256];
    int i = blockIdx.x * 256 + threadIdx.x;
    sh[threadIdx.x] = (i < NN) ? cnt[i] : 0;
    __syncthreads();
    for (int o = 128; o >= 1; o >>= 1) {
        if ((int)threadIdx.x < o) sh[threadIdx.x] += sh[threadIdx.x + o];
        __syncthreads();
    }
    if (threadIdx.x == 0) bsum[blockIdx.x] = sh[0];
}

__global__ void k_scan2(int* __restrict__ bsum, int nblk) {
    __shared__ int sh[128];
    int v = ((int)threadIdx.x < nblk) ? bsum[threadIdx.x] : 0;
    sh[threadIdx.x] = v;
    __syncthreads();
    for (int o = 1; o < 128; o <<= 1) {
        int t = (threadIdx.x >= (unsigned)o) ? sh[threadIdx.x - o] : 0;
        __syncthreads();
        sh[threadIdx.x] += t;
        __syncthreads();
    }
    if ((int)threadIdx.x < nblk) bsum[threadIdx.x] = sh[threadIdx.x];
}

// scan3 + fill_self fused
__global__ void k_scan3(const int* __restrict__ cnt, const int* __restrict__ bsum,
                        int* __restrict__ row_ptr, int* __restrict__ col_src,
                        int* __restrict__ cur) {
    __shared__ int sh[256];
    int i = blockIdx.x * 256 + threadIdx.x;
    int v = (i < NN) ? cnt[i] : 0;
    sh[threadIdx.x] = v;
    __syncthreads();
    for (int o = 1; o < 256; o <<= 1) {
        int t = (threadIdx.x >= (unsigned)o) ? sh[threadIdx.x - o] : 0;
        __syncthreads();
        sh[threadIdx.x] += t;
        __syncthreads();
    }
    int base = blockIdx.x ? bsum[blockIdx.x - 1] : 0;
    if (i < NN) {
        int incl = base + sh[threadIdx.x];
        row_ptr[i + 1] = incl;
        int p = incl - v;
        col_src[p] = i;            // self loop first
        cur[i] = p + 1;
    }
    if (i == 0) row_ptr[0] = 0;
}

__global__ void k_fill_edges(const int* __restrict__ src, const int* __restrict__ dst,
                             int* __restrict__ cur, int* __restrict__ col_src) {
    int e = blockIdx.x * 256 + threadIdx.x;
    if (e < NE) { int p = atomicAdd(&cur[dst[e]], 1); col_src[p] = src[e]; }
}

// ---------------- one cast/init kernel for everything ----------------
// regions: x 3200000 | Wl1 49152 | Wr1 49152 | W1 49152 | Wl2 49152 | Wr2 49152
//          | W2 98304 | fb1 768 | fb2 768 | cnt 25000 | stats 512
__global__ void k_cast_all(const float* __restrict__ x,
                           const float* __restrict__ Wl1, const float* __restrict__ Wr1,
                           const float* __restrict__ W1,
                           const float* __restrict__ Wl2, const float* __restrict__ Wr2,
                           const float* __restrict__ W2,
                           const float* __restrict__ bl1, const float* __restrict__ br1,
                           const float* __restrict__ bl2, const float* __restrict__ br2,
                           u16* __restrict__ xb, u16* __restrict__ WfT1,
                           u16* __restrict__ W1T, u16* __restrict__ WfT2,
                           u16* __restrict__ W2T,
                           float* __restrict__ fb1, float* __restrict__ fb2,
                           int* __restrict__ cnt, float* __restrict__ stats) {
    int i = blockIdx.x * 256 + threadIdx.x;
    if (i < 3200000) { xb[i] = (u16)bf16_1(x[i]); return; }
    i -= 3200000;
    if (i < 49152) { int k = i / 384, n = i - k * 384; WfT1[n * 128 + k] = (u16)bf16_1(Wl1[i]); return; }
    i -= 49152;
    if (i < 49152) { int k = i / 384, n = i - k * 384; WfT1[(384 + n) * 128 + k] = (u16)bf16_1(Wr1[i]); return; }
    i -= 49152;
    if (i < 49152) { int k = i / 128, n = i - k * 128; W1T[n * 384 + k] = (u16)bf16_1(W1[i]); return; }
    i -= 49152;
    if (i < 49152) { int k = i / 384, n = i - k * 384; WfT2[n * 128 + k] = (u16)bf16_1(Wl2[i]); return; }
    i -= 49152;
    if (i < 49152) { int k = i / 384, n = i - k * 384; WfT2[(384 + n) * 128 + k] = (u16)bf16_1(Wr2[i]); return; }
    i -= 49152;
    if (i < 98304) { int k = i / 128, n = i - k * 128; W2T[n * 768 + k] = (u16)bf16_1(W2[i]); return; }
    i -= 98304;
    if (i < 768) { fb1[i] = (i < 384) ? bl1[i] : br1[i - 384]; return; }
    i -= 768;
    if (i < 768) { fb2[i] = (i < 384) ? bl2[i] : br2[i - 384]; return; }
    i -= 768;
    if (i < 25000) { cnt[i] = 1; return; }   // self loop
    i -= 25000;
    if (i < 512) stats[i] = 0.f;
}
#define CAST_TOTAL (3200000 + 5 * 49152 + 98304 + 1536 + 25000 + 512)

// ---------------- bf16 MFMA GEMM: C[M,N] = A[M,K] @ BT[N,K]^T (+bias) ----------------
// BM=128 BN=64 BK=64. Staging via global_load_lds width=16 with XOR-swizzled
// SOURCE addressing: LDS unit L (16B) holds global unit (r=L>>3, c8=(L&7)^(r&7)),
// so fragment reads land 2-way-conflict-free (free per m136).
// split!=0: Cb is XL base; cols>=384 go to XL + NN*384 (XR), row stride 384.
__global__ __launch_bounds__(256) void k_gemm_bf(
        const u16* __restrict__ A, const u16* __restrict__ BT,
        const float* __restrict__ bias,
        float* __restrict__ Cf, u16* __restrict__ Cb,
        int M, int N, int K, int lda, int split) {
    __shared__ short sA[128 * 64];
    __shared__ short sB[64 * 64];
    int tid = threadIdx.x;
    int wv = tid >> 6, lane = tid & 63;
    int quad = lane >> 4, m16 = lane & 15;
    int sw = m16 & 7;
    int mb = blockIdx.y * 128, nb = blockIdx.x * 64;

    floatx4 acc[2][4];
#pragma unroll
    for (int mf = 0; mf < 2; ++mf)
#pragma unroll
        for (int nf = 0; nf < 4; ++nf)
#pragma unroll
            for (int r = 0; r < 4; ++r) acc[mf][nf][r] = 0.f;

    for (int k0 = 0; k0 < K; k0 += 64) {
        // A: 1024 16B units, 4 chunks of 64 per wave
#pragma unroll
        for (int j = 0; j < 4; ++j) {
            int L = (wv * 4 + j) * 64 + lane;
            int r = L >> 3, c8 = (L & 7) ^ (r & 7);
            int gr = mb + r; gr = gr < M ? gr : M - 1;
            __builtin_amdgcn_global_load_lds(
                (const __attribute__((address_space(1))) void*)(A + (size_t)gr * lda + k0 + c8 * 8),
                (__attribute__((address_space(3))) void*)(sA + (size_t)(wv * 4 + j) * 512),
                16, 0, 0);
        }
        // B: 512 units, 2 chunks per wave
#pragma unroll
        for (int j = 0; j < 2; ++j) {
            int L = (wv * 2 + j) * 64 + lane;
            int r = L >> 3, c8 = (L & 7) ^ (r & 7);
            __builtin_amdgcn_global_load_lds(
                (const __attribute__((address_space(1))) void*)(BT + (size_t)(nb + r) * K + k0 + c8 * 8),
                (__attribute__((address_space(3))) void*)(sB + (size_t)(wv * 2 + j) * 512),
                16, 0, 0);
        }
        __syncthreads();
#pragma unroll
        for (int ks = 0; ks < 2; ++ks) {
            int t = (ks * 4 + quad) ^ sw;
            const short* pa = sA + t * 8;
            const short* pb = sB + t * 8;
            short8 a0 = *(const short8*)(pa + (wv * 32 + m16) * 64);
            short8 a1 = *(const short8*)(pa + (wv * 32 + 16 + m16) * 64);
            short8 b0 = *(const short8*)(pb + m16 * 64);
            short8 b1 = *(const short8*)(pb + (16 + m16) * 64);
            short8 b2 = *(const short8*)(pb + (32 + m16) * 64);
            short8 b3 = *(const short8*)(pb + (48 + m16) * 64);
            acc[0][0] = __builtin_amdgcn_mfma_f32_16x16x32_bf16(a0, b0, acc[0][0], 0, 0, 0);
            acc[0][1] = __builtin_amdgcn_mfma_f32_16x16x32_bf16(a0, b1, acc[0][1], 0, 0, 0);
            acc[0][2] = __builtin_amdgcn_mfma_f32_16x16x32_bf16(a0, b2, acc[0][2], 0, 0, 0);
            acc[0][3] = __builtin_amdgcn_mfma_f32_16x16x32_bf16(a0, b3, acc[0][3], 0, 0, 0);
            acc[1][0] = __builtin_amdgcn_mfma_f32_16x16x32_bf16(a1, b0, acc[1][0], 0, 0, 0);
            acc[1][1] = __builtin_amdgcn_mfma_f32_16x16x32_bf16(a1, b1, acc[1][1], 0, 0, 0);
            acc[1][2] = __builtin_amdgcn_mfma_f32_16x16x32_bf16(a1, b2, acc[1][2], 0, 0, 0);
            acc[1][3] = __builtin_amdgcn_mfma_f32_16x16x32_bf16(a1, b3, acc[1][3], 0, 0, 0);
        }
        __syncthreads();
    }
    // epilogue: C/D layout col=lane&15, row=quad*4+reg
    u16* cbase = Cb;
    int coff = 0, ldcb = N;
    if (split) {
        ldcb = 384;
        if (nb >= 384) { cbase = Cb + (size_t)NN * 384; coff = 384; }
    }
#pragma unroll
    for (int mf = 0; mf < 2; ++mf) {
        int rbase = mb + wv * 32 + mf * 16 + quad * 4;
#pragma unroll
        for (int nf = 0; nf < 4; ++nf) {
            int col = nb + nf * 16 + m16;
            float bv = bias ? bias[col] : 0.f;
#pragma unroll
            for (int r = 0; r < 4; ++r) {
                int row = rbase + r;
                if (row < M) {
                    float v = acc[mf][nf][r] + bv;
                    if (Cf) Cf[(size_t)row * N + col] = v;
                    if (Cb) cbase[(size_t)row * ldcb + col - coff] = (u16)bf16_1(v);
                }
            }
        }
    }
}

// ---------------- GATv2 aggregate: one wave per dst, 4 edge streams of 16 lanes --------
// XL/XR: separate [NN][192]-dword bf16 tables. Lane (g,gl): group g processes
// edges e0+g, e0+g+4, ...; lane gl holds dims [8gl,8gl+8) of each head.
// Deferred-rescale online softmax: fast path (p<=m) is 1 exp + fma only.
// Flash-merge of 4 group states at end (shfl_xor 16,32), -1e30 empty sentinel.
__global__ __launch_bounds__(256) void k_gat(const u32* __restrict__ XL,
                                             const u32* __restrict__ XR,
                                             const float* __restrict__ att,
                                             const float* __restrict__ bias,
                                             const int* __restrict__ row_ptr,
                                             const int* __restrict__ col_src,
                                             u32* __restrict__ outb) {
    int node = blockIdx.x * 4 + (threadIdx.x >> 6);
    int lane = threadIdx.x & 63;
    int g = lane >> 4, gl = lane & 15;

    const u32* xrp = XR + (size_t)node * 192 + 4 * gl;
    float xr_f[3][8], att_f[3][8], acc[3][8];
    float m[3], l[3];
#pragma unroll
    for (int h = 0; h < 3; ++h) {
        uint4 ur = *(const uint4*)(xrp + h * 64);
        xr_f[h][0] = blo(ur.x); xr_f[h][1] = bhi(ur.x);
        xr_f[h][2] = blo(ur.y); xr_f[h][3] = bhi(ur.y);
        xr_f[h][4] = blo(ur.z); xr_f[h][5] = bhi(ur.z);
        xr_f[h][6] = blo(ur.w); xr_f[h][7] = bhi(ur.w);
        *(float4*)&att_f[h][0] = *(const float4*)&att[h * 128 + 8 * gl];
        *(float4*)&att_f[h][4] = *(const float4*)&att[h * 128 + 8 * gl + 4];
#pragma unroll
        for (int k = 0; k < 8; ++k) acc[h][k] = 0.f;
        m[h] = -1e30f; l[h] = 0.f;
    }

    int e0 = row_ptr[node];
    int cntE = row_ptr[node + 1] - e0;

    uint4 u0 = {}, u1 = {}, u2 = {};
    if (g < cntE) {
        int s = col_src[e0 + g];
        const u32* xp = XL + (size_t)s * 192 + 4 * gl;
        u0 = *(const uint4*)(xp);
        u1 = *(const uint4*)(xp + 64);
        u2 = *(const uint4*)(xp + 128);
    }
    for (int t = g; t < cntE; t += 4) {
        float xv[3][8];
        xv[0][0] = blo(u0.x); xv[0][1] = bhi(u0.x); xv[0][2] = blo(u0.y); xv[0][3] = bhi(u0.y);
        xv[0][4] = blo(u0.z); xv[0][5] = bhi(u0.z); xv[0][6] = blo(u0.w); xv[0][7] = bhi(u0.w);
        xv[1][0] = blo(u1.x); xv[1][1] = bhi(u1.x); xv[1][2] = blo(u1.y); xv[1][3] = bhi(u1.y);
        xv[1][4] = blo(u1.z); xv[1][5] = bhi(u1.z); xv[1][6] = blo(u1.w); xv[1][7] = bhi(u1.w);
        xv[2][0] = blo(u2.x); xv[2][1] = bhi(u2.x); xv[2][2] = blo(u2.y); xv[2][3] = bhi(u2.y);
        xv[2][4] = blo(u2.z); xv[2][5] = bhi(u2.z); xv[2][6] = blo(u2.w); xv[2][7] = bhi(u2.w);
        int tn = t + 4;
        if (tn < cntE) {
            int s = col_src[e0 + tn];
            const u32* xp = XL + (size_t)s * 192 + 4 * gl;
            u0 = *(const uint4*)(xp);
            u1 = *(const uint4*)(xp + 64);
            u2 = *(const uint4*)(xp + 128);
        }
        float p[3];
#pragma unroll
        for (int h = 0; h < 3; ++h) {
            float ph = 0.f;
#pragma unroll
            for (int k = 0; k < 8; ++k) {
                float v = xv[h][k] + xr_f[h][k];
                float lt = fmaxf(v, NEG * v);      // leaky-relu, 2 ops
                ph = fmaf(lt, att_f[h][k], ph);
            }
            p[h] = ph;
        }
#pragma unroll
        for (int o = 1; o <= 8; o <<= 1) {
            p[0] += __shfl_xor(p[0], o);
            p[1] += __shfl_xor(p[1], o);
            p[2] += __shfl_xor(p[2], o);
        }
#pragma unroll
        for (int h = 0; h < 3; ++h) {
            if (p[h] <= m[h]) {                    // common fast path
                float w = __expf(p[h] - m[h]);
                l[h] += w;
#pragma unroll
                for (int k = 0; k < 8; ++k) acc[h][k] = fmaf(w, xv[h][k], acc[h][k]);
            } else {                               // new max: w == 1
                float c = __expf(m[h] - p[h]);
                l[h] = fmaf(l[h], c, 1.f);
                m[h] = p[h];
#pragma unroll
                for (int k = 0; k < 8; ++k) acc[h][k] = fmaf(acc[h][k], c, xv[h][k]);
            }
        }
    }

    // merge the 4 group states
#pragma unroll
    for (int o = 16; o <= 32; o <<= 1) {
#pragma unroll
        for (int h = 0; h < 3; ++h) {
            float mo = __shfl_xor(m[h], o);
            float lo = __shfl_xor(l[h], o);
            float mn = fmaxf(m[h], mo);
            float cs = __expf(m[h] - mn);
            float co = __expf(mo - mn);
            l[h] = l[h] * cs + lo * co;
            m[h] = mn;
#pragma unroll
            for (int k = 0; k < 8; ++k)
                acc[h][k] = acc[h][k] * cs + __shfl_xor(acc[h][k], o) * co;
        }
    }

    if (g < 3) {   // group g writes head g (state identical in all lanes)
        int h = g;
        float r = 1.f / l[h];
        float bv[8];
        *(float4*)&bv[0] = *(const float4*)&bias[h * 128 + 8 * gl];
        *(float4*)&bv[4] = *(const float4*)&bias[h * 128 + 8 * gl + 4];
        uint4 w;
        w.x = bf16_1(fmaf(acc[h][0], r, bv[0])) | (bf16_1(fmaf(acc[h][1], r, bv[1])) << 16);
        w.y = bf16_1(fmaf(acc[h][2], r, bv[2])) | (bf16_1(fmaf(acc[h][3], r, bv[3])) << 16);
        w.z = bf16_1(fmaf(acc[h][4], r, bv[4])) | (bf16_1(fmaf(acc[h][5], r, bv[5])) << 16);
        w.w = bf16_1(fmaf(acc[h][6], r, bv[6])) | (bf16_1(fmaf(acc[h][7], r, bv[7])) << 16);
        *(uint4*)(outb + (size_t)node * 384 + h * 64 + 4 * gl) = w;
    }
}

// ---------------- BatchNorm (axis=0 over N rows, 128 cols) ----------------

__global__ void k_bn_stats(const float* __restrict__ y, float* __restrict__ stats) {
    int col = threadIdx.x & 127;
    int half = threadIdx.x >> 7;
    float s = 0.f, q = 0.f;
    for (int r = blockIdx.x * 2 + half; r < NN; r += gridDim.x * 2) {
        float v = y[(size_t)r * DD + col];
        s += v; q += v * v;
    }
    __shared__ float sh[256], shq[256];
    sh[threadIdx.x] = s; shq[threadIdx.x] = q;
    __syncthreads();
    if (half == 0) {
        atomicAdd(&stats[col], sh[col] + sh[col + 128]);
        atomicAdd(&stats[128 + col], shq[col] + shq[col + 128]);
    }
}

// finalize folded in: recompute scale/shift from raw sums per thread
__global__ void k_bn_apply(float* __restrict__ y, const float* __restrict__ stats,
                           const float* __restrict__ g, const float* __restrict__ be,
                           u16* __restrict__ yb, int wf) {
    int idx = blockIdx.x * 256 + threadIdx.x;
    if (idx < NN * DD) {
        int c = idx & 127;
        const float minv = 1.f / (float)NN;
        float mu = stats[c] * minv;
        float var = stats[128 + c] * minv - mu * mu;
        float sc = g[c] * rsqrtf(var + EPS);
        float sh = be[c] - mu * sc;
        float v = fmaxf(fmaf(y[idx], sc, sh), 0.f);
        if (wf) y[idx] = v;
        if (yb) yb[idx] = (u16)bf16_1(v);
    }
}

// ---------------- launch ----------------

extern "C" void kernel_launch(void* const* d_in, const int* in_sizes, int n_in,
                              void* d_out, int out_size, void* d_ws, size_t ws_size,
                              hipStream_t stream) {
    const float* x    = (const float*)d_in[0];
    const int*   ei   = (const int*)d_in[1];
    const float* Wl1  = (const float*)d_in[2];
    const float* bl1  = (const float*)d_in[3];
    const float* Wr1  = (const float*)d_in[4];
    const float* br1  = (const float*)d_in[5];
    const float* att1 = (const float*)d_in[6];
    const float* bc1  = (const float*)d_in[7];
    const float* g1   = (const float*)d_in[8];
    const float* be1  = (const float*)d_in[9];
    const float* Wl2  = (const float*)d_in[10];
    const float* bl2  = (const float*)d_in[11];
    const float* Wr2  = (const float*)d_in[12];
    const float* br2  = (const float*)d_in[13];
    const float* att2 = (const float*)d_in[14];
    const float* bc2  = (const float*)d_in[15];
    const float* g2   = (const float*)d_in[16];
    const float* be2  = (const float*)d_in[17];
    const float* W1   = (const float*)d_in[18];
    const float* b1   = (const float*)d_in[19];
    const float* W2   = (const float*)d_in[20];
    const float* b2   = (const float*)d_in[21];
    const int* esrc = ei;
    const int* edst = ei + NE;
    float* out = (float*)d_out;

    // ---- workspace layout (all regions 16B-aligned) ----
    float* bufD   = (float*)d_ws;          // mid fp32 [NN,128]      12.8 MB
    float* stats  = bufD + 3200000;        // 512 f (BN1 +0, BN2 +256)
    int* row_ptr  = (int*)(stats + 512);   // 25002
    int* cnt      = row_ptr + 25002;       // 25000
    int* col_src  = cnt + 25000;           // 425000
    int* bsum     = col_src + 425000;      // 132 (pad)
    float* fb1    = (float*)(bsum + 132);  // 768 fused bias L1
    float* fb2    = fb1 + 768;             // 768 fused bias L2
    u16* xb       = (u16*)(fb2 + 768);     // x bf16 [NN,128]         6.4 MB
    u16* XL       = xb + 3200000;          // [NN,384] bf16          19.2 MB
    u16* XR       = XL + 9600000;          // [NN,384] bf16 (MUST follow XL: split GEMM)
    u16* bufCat   = XR + 9600000;          // [NN,768] h2|x_in bf16  38.4 MB
    u16* bufDb    = bufCat + 19200000;     // h bf16 [NN,128]         6.4 MB
    u16* WfT1     = bufDb + 3200000;       // [768][128]
    u16* W1T      = WfT1 + 98304;          // [128][384]
    u16* WfT2     = W1T + 49152;           // [768][128]
    u16* W2T      = WfT2 + 98304;          // [128][768]

    // casts + transposes + fused biases + cnt init + stats zero, one kernel
    k_cast_all<<<(CAST_TOTAL + 255) / 256, 256, 0, stream>>>(
        x, Wl1, Wr1, W1, Wl2, Wr2, W2, bl1, br1, bl2, br2,
        xb, WfT1, W1T, WfT2, W2T, fb1, fb2, cnt, stats);

    // CSR (rebuilt every call — identical work each call)
    k_count<<<(NE + 255) / 256, 256, 0, stream>>>(edst, cnt);
    k_scan1<<<98, 256, 0, stream>>>(cnt, bsum);
    k_scan2<<<1, 128, 0, stream>>>(bsum, 98);
    k_scan3<<<98, 256, 0, stream>>>(cnt, bsum, row_ptr, col_src, cnt);
    k_fill_edges<<<(NE + 255) / 256, 256, 0, stream>>>(esrc, edst, cnt, col_src);

    dim3 blk(256);
    dim3 g768(12, (NN + 127) / 128);
    dim3 g128(2, (NN + 127) / 128);

    // layer 1: [xl|xr] = x @ [Wl1|Wr1] -> XL,XR (split)
    k_gemm_bf<<<g768, blk, 0, stream>>>(xb, WfT1, fb1, nullptr, XL, NN, 768, DD, DD, 1);
    k_gat<<<NN / 4, 256, 0, stream>>>((const u32*)XL, (const u32*)XR, att1, bc1,
                                      row_ptr, col_src, (u32*)bufCat + 192);

    // mid MLP + BN + relu  (A = x_in at bufCat cols 384.., lda=768)
    k_gemm_bf<<<g128, blk, 0, stream>>>(bufCat + 384, W1T, b1, bufD, nullptr, NN, DD, HD, 768, 0);
    k_bn_stats<<<128, 256, 0, stream>>>(bufD, stats);
    k_bn_apply<<<(NN * DD + 255) / 256, 256, 0, stream>>>(bufD, stats, g1, be1, bufDb, 0);

    // layer 2
    k_gemm_bf<<<g768, blk, 0, stream>>>(bufDb, WfT2, fb2, nullptr, XL, NN, 768, DD, DD, 1);
    k_gat<<<NN / 4, 256, 0, stream>>>((const u32*)XL, (const u32*)XR, att2, bc2,
                                      row_ptr, col_src, (u32*)bufCat);

    // final: concat([h2, x_in]) @ W2 + b2 as one K=768 GEMM, then BN+relu
    k_gemm_bf<<<g128, blk, 0, stream>>>(bufCat, W2T, b2, out, nullptr, NN, DD, 768, 768, 0);
    k_bn_stats<<<128, 256, 0, stream>>>(out, stats + 256);
    k_bn_apply<<<(NN * DD + 255) / 256, 256, 0, stream>>>(out, stats + 256, g2, be2, nullptr, 1);
}